// Round 10
// baseline (1525.019 us; speedup 1.0000x reference)
//
#include <hip/hip_runtime.h>
#include <hip/hip_bf16.h>

static constexpr int H_ = 1024;
static constexpr int W_ = 1024;
static constexpr int STR_ = 16;
static constexpr int NH_ = 63;
static constexpr int NPATCH_ = NH_ * NH_;  // 3969

typedef short bf16x8 __attribute__((ext_vector_type(8)));
typedef short short4v __attribute__((ext_vector_type(4)));
typedef float f32x4 __attribute__((ext_vector_type(4)));

// ---------------------------------------------------------------------------
// R10: K-SPLIT DECONV2 -> 2 BLOCKS/CU. Every counter since R2 says the block
// is a barrier-serialized latency chain with no pipe >20% busy and only
// 4 waves/SIMD to fill bubbles. The 83KB live set blocked 2-block residency;
// splitting deconv2's K axis breaks it: sH2 holds only 32 of 60 conv2 output
// channels at a time (S2a -> S3a(K=0..31) -> S2b -> S3b(K=32..63), acc3
// accumulates across passes). Same MFMA/B-load totals; S2's sH1 A-reads run
// twice (cheap). Live set ~64KB -> 2 blocks/CU = 8 waves/SIMD.
// VGPR MUST stay <=64 for 32 waves/CU -> __launch_bounds__(1024,8); bias/
// lin_w/dwp preloads moved to use sites to cut long-lived registers.
// Back to 1 patch/block (R7 merge: proven null; blocks residency).
//
// LDS (bytes), total 65424 (x2 = ~131KB < 160KB):
//   sH1:   [0, 30000)        625 rows x 48B ([pixel u*25+v][24ch bf16])
//   gap16: [30000, 30016)    ZEROED in S0 (S2/S4b quad3 overread of row 624)
//   sH2h:  [30016, 65296)    441 rows x 80B (32ch bf16 + 16B pad; 80B stride
//                            is non-pow2 -> S3 A-reads ~2-way banked, and
//                            16B-aligned so single b128 reads)
//   zrow:  [65296, 65424)    ZEROED in S0 (S3 invalid-tap reads)
//   overlays (dead windows):
//     CP0 [30016, 35136) CP1 [35136, 40256)   patch stage (dead before S2a)
//     sWc [30016, 34112) sp [34112, 38208)    epilogue (after S3b)
// ---------------------------------------------------------------------------
static constexpr int GAP16 = 30000;
static constexpr int SH2H  = 30016;
static constexpr int SH2S  = 80;         // bytes/row
static constexpr int ZROW  = 65296;
static constexpr int CP0   = 30016;
static constexpr int CP1   = 35136;
static constexpr int SWC   = 30016;
static constexpr int SPA   = 34112;
static constexpr int LDS_BYTES = 65424;

__device__ __forceinline__ unsigned short f2bf(float x) {
    __hip_bfloat16 b = __float2bfloat16(x);
    return __builtin_bit_cast(unsigned short, b);
}

__device__ __forceinline__ f32x4 mfma_bf16(bf16x8 a, bf16x8 b, f32x4 c) {
    return __builtin_amdgcn_mfma_f32_16x16x32_bf16(a, b, c, 0, 0, 0);
}

// fast ELU negative branch (R3: VALU cycles convert 1:1 to time here)
__device__ __forceinline__ float elu_neg(float x) { return __expf(x) - 1.f; }

__global__ __launch_bounds__(1024, 8) void fused_patch_kernel(
    const float* __restrict__ x1, const float* __restrict__ x2,
    const float* __restrict__ c1b, const float* __restrict__ c2b,
    const float* __restrict__ d2b, const float* __restrict__ d1b,
    const float* __restrict__ lin_w, const float* __restrict__ lin_b,
    const unsigned short* __restrict__ w1frag,   // conv1 B frags, bf16
    const unsigned short* __restrict__ w2frag,   // conv2 B frags, bf16
    const unsigned short* __restrict__ dw2frag,  // deconv2 B frags, bf16
    const float* __restrict__ dw1,               // raw deconv1_w (24,1,2,8,8)
    float* __restrict__ recon)                   // = d_out (atomic overlap-add)
{
    __shared__ alignas(16) char sbuf[LDS_BYTES];
    const int n  = blockIdx.x;
    const int t  = (int)threadIdx.x;
    const int pi = n / NH_, pj = n % NH_;
    const int Y0 = pi * STR_, X0 = pj * STR_;
    const int wv = t >> 6, lane = t & 63;
    const int ln15 = lane & 15, quad = lane >> 4;

    // conv1 weights preloaded (dead after S1; latency overlaps S0 staging)
    bf16x8 w1b[8];
    #pragma unroll
    for (int gg = 0; gg < 8; ++gg)
        w1b[gg] = *(const bf16x8*)(w1frag + (gg * 64 + lane) * 8);

    // ---- S0: zero hazard windows; stage patch [2][32][40ch] x 2 parity copies ----
    if (t < 4)       ((float*)(sbuf + GAP16))[t] = 0.f;
    else if (t < 36) ((float*)(sbuf + ZROW))[t - 4] = 0.f;
    for (int k = t; k < 2048; k += 1024) {
        int d = k >> 10, r = k & 1023, y = r >> 5, x = r & 31;
        unsigned short bb = f2bf((d ? x2 : x1)[(Y0 + y) * W_ + (X0 + x)]);
        int row = (d * 32 + y) * 40;
        ((unsigned short*)(sbuf + CP0))[row + x] = bb;
        if (x > 0) ((unsigned short*)(sbuf + CP1))[row + x - 1] = bb;
    }
    __syncthreads();

    // ---- S1: conv1. Linear M=625 (40 mtiles), N=32, K=128. Swapped MFMA:
    //      pixel on ln15, channel on quad*4+r -> ds_write_b64 writeback. ----
    {
        const f32x4 c1bq0 = *(const f32x4*)(c1b + quad * 4);
        f32x4 c1bq1 = (f32x4){0.f, 0.f, 0.f, 0.f};
        if (quad < 2) c1bq1 = *(const f32x4*)(c1b + 16 + quad * 4);
        for (int tl = wv; tl < 40; tl += 16) {
            const int rawm = tl * 16 + ln15;
            int m = rawm > 624 ? 624 : rawm;            // junk lanes clamp (read)
            int u = m / 25, v = m - u * 25;
            const char* cps = sbuf + ((v & 1) ? CP1 : CP0);
            const int vb2 = (v & ~1) * 2;
            f32x4 acc[2];
            acc[0] = (f32x4){0.f, 0.f, 0.f, 0.f};
            acc[1] = (f32x4){0.f, 0.f, 0.f, 0.f};
            #pragma unroll
            for (int kc = 0; kc < 4; ++kc) {
                const int idx8 = kc * 4 + quad;
                const int dd = idx8 >> 3, pp = idx8 & 7;
                const unsigned int* ap = (const unsigned int*)(cps + (dd * 32 + u + pp) * 80 + vb2);
                union { unsigned int u4[4]; bf16x8 v8; } af;
                af.u4[0] = ap[0]; af.u4[1] = ap[1]; af.u4[2] = ap[2]; af.u4[3] = ap[3];
                acc[0] = mfma_bf16(w1b[kc * 2 + 0], af.v8, acc[0]);
                acc[1] = mfma_bf16(w1b[kc * 2 + 1], af.v8, acc[1]);
            }
            if (rawm < 625) {
                char* rowp = sbuf + rawm * 48;
                short4v p0;
                #pragma unroll
                for (int r = 0; r < 4; ++r) {
                    float hv = acc[0][r] + c1bq0[r];
                    hv = hv > 0.f ? hv : elu_neg(hv);
                    p0[r] = (short)f2bf(hv);
                }
                *(short4v*)(rowp + quad * 8) = p0;
                if (quad < 2) {
                    short4v p1;
                    #pragma unroll
                    for (int r = 0; r < 4; ++r) {
                        float hw = acc[1][r] + c1bq1[r];
                        hw = hw > 0.f ? hw : elu_neg(hw);
                        p1[r] = (short)f2bf(hw);
                    }
                    *(short4v*)(rowp + 32 + quad * 8) = p1;
                }
            }
        }
    }
    __syncthreads();

    // ---- S2/S3 K-split machinery ----
    int abase2[2];
    if (wv < 14) {
        #pragma unroll
        for (int i = 0; i < 2; ++i) {
            int mm = (wv + i * 14) * 16 + ln15;
            if (mm > 440) mm = 440;          // M-pad: valid row, discarded on write
            int y = mm / 21, x = mm - y * 21;
            abase2[i] = (y * 25 + x) * 48;
        }
    }
    f32x4 acc3[3][2];                        // deconv2 acc, persists across passes
    int uarr[3], varr[3], aoff3[3];
    bool mval[3];
    #pragma unroll
    for (int i = 0; i < 3; ++i) {
        int m = (wv + i * 16) * 16 + ln15;
        mval[i] = (m < 625) && !(i == 2 && wv >= 8);
        int mc = (m < 625) ? m : 0;
        uarr[i] = mc / 25; varr[i] = mc - uarr[i] * 25;
        aoff3[i] = SH2H + (uarr[i] * 21 + varr[i]) * SH2S;
    }

    // conv2 pass h: output channels h*32 .. h*32+31 -> sH2h
    auto s2pass = [&](int h) {
        if (wv >= 14) return;
        f32x4 acc2[2][2];
        #pragma unroll
        for (int i = 0; i < 2; ++i) {
            acc2[i][0] = (f32x4){0.f, 0.f, 0.f, 0.f};
            acc2[i][1] = (f32x4){0.f, 0.f, 0.f, 0.f};
        }
        const unsigned short* wb = w2frag + lane * 8;
        #pragma unroll
        for (int p = 0; p < 5; ++p) {
            #pragma unroll
            for (int q = 0; q < 5; ++q) {
                const int tap  = p * 5 + q;
                const int toff = (p * 25 + q) * 48;
                bf16x8 b0 = *(const bf16x8*)(wb + (tap * 4 + 2 * h + 0) * 512);
                bf16x8 b1 = *(const bf16x8*)(wb + (tap * 4 + 2 * h + 1) * 512);
                #pragma unroll
                for (int i = 0; i < 2; ++i) {
                    bf16x8 a = *(const bf16x8*)(sbuf + abase2[i] + toff + quad * 16);
                    acc2[i][0] = mfma_bf16(b0, a, acc2[i][0]);   // swapped
                    acc2[i][1] = mfma_bf16(b1, a, acc2[i][1]);
                }
            }
        }
        // writeback: relu -> sH2h row pixel*80B, local ch = lnt*16+quad*4+r
        #pragma unroll
        for (int i = 0; i < 2; ++i) {
            int rawpix = (wv + i * 14) * 16 + ln15;
            if (rawpix < 441) {
                char* rowp = sbuf + SH2H + rawpix * SH2S;
                #pragma unroll
                for (int lnt = 0; lnt < 2; ++lnt) {
                    if (h == 1 && lnt == 1 && quad == 3) continue;   // ch 60..63
                    const f32x4 bq = *(const f32x4*)(c2b + h * 32 + lnt * 16 + quad * 4);
                    short4v pk;
                    #pragma unroll
                    for (int r = 0; r < 4; ++r)
                        pk[r] = (short)f2bf(fmaxf(acc2[i][lnt][r] + bq[r], 0.f));
                    *(short4v*)(rowp + lnt * 32 + quad * 8) = pk;
                }
            }
        }
    };

    // deconv2 pass h: accumulate K = h*32 .. h*32+31 into acc3
    auto s3pass = [&](int h) {
        const unsigned short* db = dw2frag + lane * 8 + h * 1024;
        #pragma unroll
        for (int dy = 0; dy < 5; ++dy) {
            #pragma unroll
            for (int dx = 0; dx < 5; ++dx) {
                const int tap = dy * 5 + dx;
                const int t2o = (dy * 21 + dx) * SH2S;
                bf16x8 b0 = *(const bf16x8*)(db + tap * 2048);
                bf16x8 b1 = *(const bf16x8*)(db + tap * 2048 + 512);
                #pragma unroll
                for (int i = 0; i < 3; ++i) {
                    if (i == 2 && wv >= 8) continue;                 // wave-uniform
                    int yv = uarr[i] - dy, xv = varr[i] - dx;
                    bool ok = mval[i] && ((unsigned)yv < 21u) && ((unsigned)xv < 21u);
                    int ra = ok ? (aoff3[i] - t2o) : ZROW;           // zero row -> +0
                    bf16x8 a = *(const bf16x8*)(sbuf + ra + quad * 16);  // b128, aligned
                    acc3[i][0] = mfma_bf16(b0, a, acc3[i][0]);       // swapped
                    acc3[i][1] = mfma_bf16(b1, a, acc3[i][1]);
                }
            }
        }
    };

    s2pass(0);
    #pragma unroll
    for (int i = 0; i < 3; ++i) {
        acc3[i][0] = (f32x4){0.f, 0.f, 0.f, 0.f};
        acc3[i][1] = (f32x4){0.f, 0.f, 0.f, 0.f};
    }
    __syncthreads();     // sH2h(ch0-31) ready
    s3pass(0);
    __syncthreads();     // all S3a reads done -> safe to overwrite sH2h
    s2pass(1);
    __syncthreads();     // sH2h(ch32-59) ready
    s3pass(1);
    __syncthreads();     // sH1/CP/sH2h dead from here

    // ---- S4a: h3 = elu(acc3 + d2b) -> [0,30000); sWc; zero sp ----
    const float lw0 = lin_w[2 * n], lw1 = lin_w[2 * n + 1];
    float* sp = (float*)(sbuf + SPA);
    {
        const f32x4 d2bq0 = *(const f32x4*)(d2b + quad * 4);
        f32x4 d2bq1 = (f32x4){0.f, 0.f, 0.f, 0.f};
        if (quad < 2) d2bq1 = *(const f32x4*)(d2b + 16 + quad * 4);
        #pragma unroll
        for (int i = 0; i < 3; ++i) {
            if (i == 2 && wv >= 8) continue;
            int pix = (wv + i * 16) * 16 + ln15;
            if (pix < 625) {
                char* rowp = sbuf + pix * 48;
                short4v p0;
                #pragma unroll
                for (int r = 0; r < 4; ++r) {
                    float hv = acc3[i][0][r] + d2bq0[r];
                    hv = hv > 0.f ? hv : elu_neg(hv);
                    p0[r] = (short)f2bf(hv);
                }
                *(short4v*)(rowp + quad * 8) = p0;
                if (quad < 2) {
                    short4v p1;
                    #pragma unroll
                    for (int r = 0; r < 4; ++r) {
                        float hw = acc3[i][1][r] + d2bq1[r];
                        hw = hw > 0.f ? hw : elu_neg(hw);
                        p1[r] = (short)f2bf(hw);
                    }
                    *(short4v*)(rowp + 32 + quad * 8) = p1;
                }
            }
        }
    }
    {   // sWc: 64 r x 32 c (dw1 gathered here; region dead since S3b)
        int r0 = t >> 5, c0 = t & 31;
        float a0 = 0.f, a1 = 0.f;
        if (c0 < 24) {
            a0 = dw1[(c0 * 2 + 0) * 64 + r0];
            a1 = dw1[(c0 * 2 + 1) * 64 + r0];
        }
        ((unsigned short*)(sbuf + SWC))[r0 * 32 + c0] = f2bf(lw0 * a0 + lw1 * a1);
        int k1 = t + 1024, r1 = k1 >> 5, c1 = k1 & 31;
        float b0v = 0.f, b1v = 0.f;
        if (c1 < 24) {
            b0v = dw1[(c1 * 2 + 0) * 64 + r1];
            b1v = dw1[(c1 * 2 + 1) * 64 + r1];
        }
        ((unsigned short*)(sbuf + SWC))[r1 * 32 + c1] = f2bf(lw0 * b0v + lw1 * b1v);
    }
    sp[t] = 0.f;
    __syncthreads();

    // ---- S4b: epilogue GEMM, scatter-add into sp (64 distinct addrs/wave-op) ----
    {
        int qoff[4];
        #pragma unroll
        for (int r = 0; r < 4; ++r) {
            int qr = quad * 4 + r;
            qoff[r] = (qr >> 3) * 32 + (qr & 7);
        }
        #pragma unroll
        for (int i = 0; i < 3; ++i) {
            int mt = wv + i * 16;
            if (mt >= 40) continue;                 // wave-uniform
            int rawpix = mt * 16 + ln15;
            bool pok = (rawpix < 625);
            int pc = pok ? rawpix : 624;
            bf16x8 a = *(const bf16x8*)(sbuf + pc * 48 + quad * 16);
            int uvbase = (pc / 25) * 32 + (pc % 25);
            #pragma unroll
            for (int nt = 0; nt < 4; ++nt) {
                bf16x8 wbv = *(const bf16x8*)(sbuf + SWC + (nt * 16 + ln15) * 64 + quad * 16);
                f32x4 acc4 = (f32x4){0.f, 0.f, 0.f, 0.f};
                acc4 = mfma_bf16(wbv, a, acc4);     // swapped
                if (pok) {
                    #pragma unroll
                    for (int r = 0; r < 4; ++r)
                        atomicAdd(&sp[uvbase + nt * 64 + qoff[r]], acc4[r]);
                }
            }
        }
    }
    __syncthreads();

    // ---- S5: overlap-add into global recon ----
    {
        const float obias = d1b[0] * (lw0 + lw1) + lin_b[n];
        int yy = t >> 5, xx = t & 31;
        atomicAdd(&recon[(Y0 + yy) * W_ + X0 + xx], sp[t] + obias);
    }
}

// ---------------------------------------------------------------------------
// Prep (layouts unchanged):
//  conv1:   i = (kc*2+nt)*512 + lane*8 + j -> n=nt*16+(lane&15), k=kc*32+(lane>>4)*8+j
//  conv2:   tap*2048 + nt*512 + lane*8 + j -> o=nt*16+ln15, c=quad*8+j (zeros o>=60, c>=24)
//  deconv2: tap*2048 + kc*1024 + nt*512 + lane*8 + j -> k=kc*32+quad*8+j, c=nt*16+ln15
//           (zeros k>=60, c>=24) -- kc chunk == K-split pass h
// ---------------------------------------------------------------------------
__global__ void prep_kernel(const float* __restrict__ c1w,
                            const float* __restrict__ c2w,
                            const float* __restrict__ d2w,
                            unsigned short* __restrict__ w1frag,
                            unsigned short* __restrict__ w2frag,
                            unsigned short* __restrict__ dw2frag)
{
    int i = blockIdx.x * blockDim.x + threadIdx.x;
    if (i < 51200) {
        int j = i & 7, lane = (i >> 3) & 63;
        int ln15 = lane & 15, quad = lane >> 4;
        if (i < 4096) {   // conv1
            int g = i >> 9;
            int kc = g >> 1, nt = g & 1;
            int nn = nt * 16 + ln15, k = kc * 32 + quad * 8 + j;
            w1frag[i] = f2bf((nn < 24) ? c1w[nn * 128 + k] : 0.f);
        }
        {   // conv2
            int nt = (i >> 9) & 3, tap = i >> 11;
            int o = nt * 16 + ln15, c = quad * 8 + j;
            float v = (o < 60 && c < 24) ? c2w[(o * 24 + c) * 25 + tap] : 0.f;
            w2frag[i] = f2bf(v);
        }
        {   // deconv2
            int nt = (i >> 9) & 1, kc = (i >> 10) & 1, tap = i >> 11;
            int k = kc * 32 + quad * 8 + j, c = nt * 16 + ln15;
            float v = (k < 60 && c < 24) ? d2w[(k * 24 + c) * 25 + tap] : 0.f;
            dw2frag[i] = f2bf(v);
        }
    }
}

__global__ void finalize_kernel(const float* __restrict__ x2,
                                const float* __restrict__ l1w,
                                float* __restrict__ out)
{
    int i = blockIdx.x * blockDim.x + threadIdx.x;
    if (i < H_ * W_) {
        float r = out[i];
        out[i] = x2[i] - r * l1w[0];
    }
}

extern "C" void kernel_launch(void* const* d_in, const int* in_sizes, int n_in,
                              void* d_out, int out_size, void* d_ws, size_t ws_size,
                              hipStream_t stream)
{
    const float* x1  = (const float*)d_in[0];
    const float* x2  = (const float*)d_in[1];
    const float* c1w = (const float*)d_in[2];
    const float* c1b = (const float*)d_in[3];
    const float* c2w = (const float*)d_in[4];
    const float* c2b = (const float*)d_in[5];
    const float* d2w = (const float*)d_in[6];
    const float* d2b = (const float*)d_in[7];
    const float* d1w = (const float*)d_in[8];
    const float* d1b = (const float*)d_in[9];
    const float* lw  = (const float*)d_in[10];
    const float* lb  = (const float*)d_in[11];
    const float* l1w = (const float*)d_in[12];

    float*          out     = (float*)d_out;
    unsigned short* w1frag  = (unsigned short*)d_ws;                      // 8192 B
    unsigned short* w2frag  = (unsigned short*)((char*)d_ws + 8192);      // 102400 B
    unsigned short* dw2frag = (unsigned short*)((char*)d_ws + 110592);    // 102400 B

    hipMemsetAsync(d_out, 0, (size_t)H_ * W_ * sizeof(float), stream);
    prep_kernel<<<100, 512, 0, stream>>>(c1w, c2w, d2w, w1frag, w2frag, dw2frag);
    fused_patch_kernel<<<NPATCH_, 1024, 0, stream>>>(x1, x2, c1b, c2b, d2b, d1b,
                                                     lw, lb, w1frag, w2frag, dw2frag,
                                                     d1w, out);
    finalize_kernel<<<(H_ * W_ + 255) / 256, 256, 0, stream>>>(x2, l1w, out);
}

// Round 11
// 1340.264 us; speedup vs baseline: 1.1378x; 1.1378x over previous
//
#include <hip/hip_runtime.h>
#include <hip/hip_bf16.h>

static constexpr int H_ = 1024;
static constexpr int W_ = 1024;
static constexpr int STR_ = 16;
static constexpr int NH_ = 63;
static constexpr int NPATCH_ = NH_ * NH_;  // 3969

typedef short bf16x8 __attribute__((ext_vector_type(8)));
typedef short short4v __attribute__((ext_vector_type(4)));
typedef float f32x4 __attribute__((ext_vector_type(4)));

// ---------------------------------------------------------------------------
// R11: DE-FUSED PIPELINE. 10 rounds of counters say the megakernel is a
// barrier-serialized latency chain: no pipe >20%, HBM 0.3% used, every
// latency-hiding attempt null. De-fuse into 4 per-layer kernels with global
// bf16 intermediates (h1 122MB, h2 211MB, h3 aliases h1): blocks become
// independent (no cross-phase lockstep), LDS per block 10-53KB -> 3-8
// blocks/CU, and the idle HBM absorbs ~1GB of traffic (~200-300us at
// achievable BW). Host branches on ws_size: < NEED -> proven R9 fused
// fallback (1338us).
//
// ws layout: [0,212992) weight frags | h1 [212992, +122118192) slab 30768
//            (641 rows x 48B, row 625 zeroed = K-overread pad) |
//            h2 [+...] slab 53248 (441 rows x 120B used).  h3 == h1 (h1 dead
//            after k_conv2; k_deconv2 rewrites rows 0-624 fully, row 625
//            stays zero).
// ---------------------------------------------------------------------------
static constexpr size_t FRAG_BYTES = 212992;
static constexpr size_t H1_SLAB    = 30768;          // 641*48, 16B-aligned
static constexpr size_t H2_SLAB    = 53248;
static constexpr size_t H1_BYTES   = (size_t)NPATCH_ * H1_SLAB;   // 122,118,192
static constexpr size_t H2_BYTES   = (size_t)NPATCH_ * H2_SLAB;   // 211,341,312
static constexpr size_t WS_NEED    = FRAG_BYTES + H1_BYTES + H2_BYTES;

__device__ __forceinline__ unsigned short f2bf(float x) {
    __hip_bfloat16 b = __float2bfloat16(x);
    return __builtin_bit_cast(unsigned short, b);
}

__device__ __forceinline__ f32x4 mfma_bf16(bf16x8 a, bf16x8 b, f32x4 c) {
    return __builtin_amdgcn_mfma_f32_16x16x32_bf16(a, b, c, 0, 0, 0);
}

__device__ __forceinline__ float elu_neg(float x) { return __expf(x) - 1.f; }

// ============================================================================
// K1: patchify + conv1.  Per patch: 625 pixels x 24ch -> h1 (bf16, 48B rows).
// LDS 10.2KB, 256 thr -> 8 blocks/CU possible.
// ============================================================================
__global__ __launch_bounds__(256) void k_conv1(
    const float* __restrict__ x1, const float* __restrict__ x2,
    const float* __restrict__ c1b, const unsigned short* __restrict__ w1frag,
    unsigned short* __restrict__ h1)
{
    __shared__ alignas(16) char sbuf[10240];     // CP0 [0,5120) CP1 [5120,10240)
    const int n = blockIdx.x, t = (int)threadIdx.x;
    const int pi = n / NH_, pj = n % NH_;
    const int Y0 = pi * STR_, X0 = pj * STR_;
    const int wv = t >> 6, lane = t & 63;
    const int ln15 = lane & 15, quad = lane >> 4;
    unsigned short* h1n = h1 + (size_t)n * (H1_SLAB / 2);

    bf16x8 w1b[8];
    #pragma unroll
    for (int g = 0; g < 8; ++g)
        w1b[g] = *(const bf16x8*)(w1frag + (g * 64 + lane) * 8);
    const f32x4 c1bq0 = *(const f32x4*)(c1b + quad * 4);
    f32x4 c1bq1 = (f32x4){0.f, 0.f, 0.f, 0.f};
    if (quad < 2) c1bq1 = *(const f32x4*)(c1b + 16 + quad * 4);

    if (t < 6) ((unsigned long long*)(h1n + 625 * 24))[t] = 0ull;  // zero pad row 625

    for (int k = t; k < 2048; k += 256) {
        int d = k >> 10, r = k & 1023, y = r >> 5, x = r & 31;
        unsigned short bb = f2bf((d ? x2 : x1)[(Y0 + y) * W_ + (X0 + x)]);
        int row = (d * 32 + y) * 40;
        ((unsigned short*)(sbuf))[row + x] = bb;
        if (x > 0) ((unsigned short*)(sbuf + 5120))[row + x - 1] = bb;
    }
    __syncthreads();

    for (int tl = wv; tl < 40; tl += 4) {
        const int rawm = tl * 16 + ln15;
        int m = rawm > 624 ? 624 : rawm;
        int u = m / 25, v = m - u * 25;
        const char* cps = sbuf + ((v & 1) ? 5120 : 0);
        const int vb2 = (v & ~1) * 2;
        f32x4 acc0 = (f32x4){0.f, 0.f, 0.f, 0.f};
        f32x4 acc1 = (f32x4){0.f, 0.f, 0.f, 0.f};
        #pragma unroll
        for (int kc = 0; kc < 4; ++kc) {
            const int idx8 = kc * 4 + quad;
            const int dd = idx8 >> 3, pp = idx8 & 7;
            const unsigned int* ap = (const unsigned int*)(cps + (dd * 32 + u + pp) * 80 + vb2);
            union { unsigned int u4[4]; bf16x8 v8; } af;
            af.u4[0] = ap[0]; af.u4[1] = ap[1]; af.u4[2] = ap[2]; af.u4[3] = ap[3];
            acc0 = mfma_bf16(w1b[kc * 2 + 0], af.v8, acc0);   // swapped: pixel on ln15
            acc1 = mfma_bf16(w1b[kc * 2 + 1], af.v8, acc1);
        }
        if (rawm < 625) {
            unsigned short* rowp = h1n + rawm * 24;
            short4v p0;
            #pragma unroll
            for (int r = 0; r < 4; ++r) {
                float hv = acc0[r] + c1bq0[r];
                hv = hv > 0.f ? hv : elu_neg(hv);
                p0[r] = (short)f2bf(hv);
            }
            *(short4v*)(rowp + quad * 4) = p0;               // ch quad*4..+3
            if (quad < 2) {
                short4v p1;
                #pragma unroll
                for (int r = 0; r < 4; ++r) {
                    float hw = acc1[r] + c1bq1[r];
                    hw = hw > 0.f ? hw : elu_neg(hw);
                    p1[r] = (short)f2bf(hw);
                }
                *(short4v*)(rowp + 16 + quad * 4) = p1;      // ch 16+quad*4..+3
            }
        }
    }
}

// ============================================================================
// K2: conv2.  Stage h1 patch (30KB incl zero row) -> LDS; 28 mtiles / 4 waves
// = 7 sequential each (acc 16 regs).  Write h2 (120B rows).  5 blocks/CU.
// ============================================================================
__global__ __launch_bounds__(256) void k_conv2(
    const float* __restrict__ c2b, const unsigned short* __restrict__ w2frag,
    const unsigned short* __restrict__ h1, unsigned short* __restrict__ h2)
{
    __shared__ alignas(16) char sbuf[30048];
    const int n = blockIdx.x, t = (int)threadIdx.x;
    const int wv = t >> 6, lane = t & 63;
    const int ln15 = lane & 15, quad = lane >> 4;
    {
        const f32x4* src = (const f32x4*)(h1 + (size_t)n * (H1_SLAB / 2));
        f32x4* dst = (f32x4*)sbuf;
        for (int i = t; i < 1878; i += 256) dst[i] = src[i];   // 30048B incl zero row
    }
    __syncthreads();

    const unsigned short* wb = w2frag + lane * 8;
    unsigned short* h2n = h2 + (size_t)n * (H2_SLAB / 2);

    for (int mt = wv; mt < 28; mt += 4) {
        int mm = mt * 16 + ln15; if (mm > 440) mm = 440;
        int y = mm / 21, x = mm - y * 21;
        const int abase = (y * 25 + x) * 48;
        f32x4 acc[4];
        #pragma unroll
        for (int nt = 0; nt < 4; ++nt) acc[nt] = (f32x4){0.f, 0.f, 0.f, 0.f};
        #pragma unroll
        for (int p = 0; p < 5; ++p) {
            #pragma unroll
            for (int q = 0; q < 5; ++q) {
                const int tap  = p * 5 + q;
                const int toff = (p * 25 + q) * 48;
                bf16x8 bfr[4];
                #pragma unroll
                for (int nt = 0; nt < 4; ++nt)
                    bfr[nt] = *(const bf16x8*)(wb + (tap * 4 + nt) * 512);
                bf16x8 a = *(const bf16x8*)(sbuf + abase + toff + quad * 16);
                #pragma unroll
                for (int nt = 0; nt < 4; ++nt)
                    acc[nt] = mfma_bf16(bfr[nt], a, acc[nt]);   // swapped
            }
        }
        int rawpix = mt * 16 + ln15;
        if (rawpix < 441) {
            unsigned short* rowp = h2n + rawpix * 60;
            #pragma unroll
            for (int nt = 0; nt < 4; ++nt) {
                if (nt == 3 && quad == 3) continue;              // ch 60..63 invalid
                const f32x4 bq = *(const f32x4*)(c2b + nt * 16 + quad * 4);
                short4v pk;
                #pragma unroll
                for (int r = 0; r < 4; ++r)
                    pk[r] = (short)f2bf(fmaxf(acc[nt][r] + bq[r], 0.f));
                *(short4v*)(rowp + nt * 16 + quad * 4) = pk;
            }
        }
    }
}

// ============================================================================
// K3: deconv2.  Stage h2 patch (52.9KB) + zrow -> LDS; 40 mtiles / 8 waves =
// 5 sequential each (acc only 8 regs -- no K-split, no cross-phase liveness).
// Write h3 (= h1 alias).  3 blocks/CU.
// ============================================================================
__global__ __launch_bounds__(512) void k_deconv2(
    const float* __restrict__ d2b, const unsigned short* __restrict__ dw2frag,
    const unsigned short* __restrict__ h2, unsigned short* __restrict__ h3)
{
    __shared__ alignas(16) char sbuf[53056];    // sH2 [0,52920) zrow [52920,53056)
    const int n = blockIdx.x, t = (int)threadIdx.x;
    const int wv = t >> 6, lane = t & 63;
    const int ln15 = lane & 15, quad = lane >> 4;
    {
        const f32x4* src = (const f32x4*)(h2 + (size_t)n * (H2_SLAB / 2));
        f32x4* dst = (f32x4*)sbuf;
        for (int i = t; i < 3307; i += 512) dst[i] = src[i];    // [0,52912)
        if (t == 0)
            *(unsigned long long*)(sbuf + 52912) =
                *(const unsigned long long*)((const char*)src + 52912);
        if (t >= 64 && t < 81)
            ((unsigned long long*)(sbuf + 52920))[t - 64] = 0ull;  // zrow 136B
    }
    __syncthreads();

    const unsigned short* db = dw2frag + lane * 8;
    const f32x4 d2bq0 = *(const f32x4*)(d2b + quad * 4);
    f32x4 d2bq1 = (f32x4){0.f, 0.f, 0.f, 0.f};
    if (quad < 2) d2bq1 = *(const f32x4*)(d2b + 16 + quad * 4);
    unsigned short* h3n = h3 + (size_t)n * (H1_SLAB / 2);

    for (int mt = wv; mt < 40; mt += 8) {
        const int m = mt * 16 + ln15;
        const bool mv = (m < 625);
        const int mc = mv ? m : 0;
        const int ua = mc / 25, va = mc - ua * 25;
        const int aoff = (ua * 21 + va) * 120;
        f32x4 accN0 = (f32x4){0.f, 0.f, 0.f, 0.f};
        f32x4 accN1 = (f32x4){0.f, 0.f, 0.f, 0.f};
        #pragma unroll
        for (int dy = 0; dy < 5; ++dy) {
            #pragma unroll
            for (int dx = 0; dx < 5; ++dx) {
                const int tap = dy * 5 + dx;
                const int t2o = (dy * 21 + dx) * 120;
                bf16x8 bc0 = *(const bf16x8*)(db + tap * 2048);
                bf16x8 bc1 = *(const bf16x8*)(db + tap * 2048 + 512);
                bf16x8 bc2 = *(const bf16x8*)(db + tap * 2048 + 1024);
                bf16x8 bc3 = *(const bf16x8*)(db + tap * 2048 + 1536);
                int yv = ua - dy, xv = va - dx;
                bool ok = mv && ((unsigned)yv < 21u) && ((unsigned)xv < 21u);
                int ra = ok ? (aoff - t2o) : 52920;             // zero row -> +0
                const char* ap = sbuf + ra + quad * 16;
                short4v lo0 = *(const short4v*)(ap);             // rows 8B-aligned
                short4v hi0 = *(const short4v*)(ap + 8);
                bf16x8 a0 = __builtin_shufflevector(lo0, hi0, 0, 1, 2, 3, 4, 5, 6, 7);
                accN0 = mfma_bf16(bc0, a0, accN0);               // swapped
                accN1 = mfma_bf16(bc1, a0, accN1);
                short4v lo1 = *(const short4v*)(ap + 64);
                short4v hi1 = *(const short4v*)(ap + 72);
                bf16x8 a1 = __builtin_shufflevector(lo1, hi1, 0, 1, 2, 3, 4, 5, 6, 7);
                accN0 = mfma_bf16(bc2, a1, accN0);
                accN1 = mfma_bf16(bc3, a1, accN1);
            }
        }
        if (m < 625) {
            unsigned short* rowp = h3n + m * 24;
            short4v p0;
            #pragma unroll
            for (int r = 0; r < 4; ++r) {
                float hv = accN0[r] + d2bq0[r];
                hv = hv > 0.f ? hv : elu_neg(hv);
                p0[r] = (short)f2bf(hv);
            }
            *(short4v*)(rowp + quad * 4) = p0;
            if (quad < 2) {
                short4v p1;
                #pragma unroll
                for (int r = 0; r < 4; ++r) {
                    float hw = accN1[r] + d2bq1[r];
                    hw = hw > 0.f ? hw : elu_neg(hw);
                    p1[r] = (short)f2bf(hw);
                }
                *(short4v*)(rowp + 16 + quad * 4) = p1;
            }
        }
    }
}

// ============================================================================
// K4: epilogue GEMM + overlap-add.  Stage h3 -> LDS; sWc; 40 mtiles / 4 waves;
// LDS-atomic scatter into sp; global atomic overlap-add.  4 blocks/CU.
// ============================================================================
__global__ __launch_bounds__(256) void k_epilogue(
    const float* __restrict__ d1b, const float* __restrict__ lin_w,
    const float* __restrict__ lin_b, const float* __restrict__ dw1,
    const unsigned short* __restrict__ h3, float* __restrict__ recon)
{
    __shared__ alignas(16) char sbuf[38240];  // h3 [0,30048) sWc [30048,34144) sp [34144,38240)
    const int n = blockIdx.x, t = (int)threadIdx.x;
    const int pi = n / NH_, pj = n % NH_;
    const int Y0 = pi * STR_, X0 = pj * STR_;
    const int wv = t >> 6, lane = t & 63;
    const int ln15 = lane & 15, quad = lane >> 4;
    const float lw0 = lin_w[2 * n], lw1 = lin_w[2 * n + 1];
    {
        const f32x4* src = (const f32x4*)(h3 + (size_t)n * (H1_SLAB / 2));
        f32x4* dst = (f32x4*)sbuf;
        for (int i = t; i < 1878; i += 256) dst[i] = src[i];
    }
    unsigned short* swc = (unsigned short*)(sbuf + 30048);
    float* sp = (float*)(sbuf + 34144);
    for (int k = t; k < 2048; k += 256) {
        int r = k >> 5, c = k & 31;
        float v = 0.f;
        if (c < 24)
            v = lw0 * dw1[(c * 2 + 0) * 64 + r] + lw1 * dw1[(c * 2 + 1) * 64 + r];
        swc[r * 32 + c] = f2bf(v);
    }
    for (int k = t; k < 1024; k += 256) sp[k] = 0.f;
    __syncthreads();

    int qoff[4];
    #pragma unroll
    for (int r = 0; r < 4; ++r) {
        int qr = quad * 4 + r;
        qoff[r] = (qr >> 3) * 32 + (qr & 7);
    }
    for (int mt = wv; mt < 40; mt += 4) {
        int rawpix = mt * 16 + ln15;
        bool pok = (rawpix < 625);
        int pc = pok ? rawpix : 624;
        bf16x8 a = *(const bf16x8*)(sbuf + pc * 48 + quad * 16);
        int uvbase = (pc / 25) * 32 + (pc % 25);
        #pragma unroll
        for (int nt = 0; nt < 4; ++nt) {
            bf16x8 wbv = *(const bf16x8*)((char*)swc + (nt * 16 + ln15) * 64 + quad * 16);
            f32x4 a4 = (f32x4){0.f, 0.f, 0.f, 0.f};
            a4 = mfma_bf16(wbv, a, a4);                          // swapped
            if (pok) {
                #pragma unroll
                for (int r = 0; r < 4; ++r)
                    atomicAdd(&sp[uvbase + nt * 64 + qoff[r]], a4[r]);
            }
        }
    }
    __syncthreads();
    const float obias = d1b[0] * (lw0 + lw1) + lin_b[n];
    for (int k = t; k < 1024; k += 256) {
        int yy = k >> 5, xx = k & 31;
        atomicAdd(&recon[(Y0 + yy) * W_ + (X0 + xx)], sp[k] + obias);
    }
}

// ============================================================================
// FALLBACK: R9 fused megakernel (proven 1338us) -- used when ws too small.
// ============================================================================
static constexpr int FGAP16 = 49200;
static constexpr int FCP0   = 49216;
static constexpr int FCP1   = 55360;
static constexpr int FSH2_0 = 49216;
static constexpr int FSH2SZ = 52920;
static constexpr int FSH2_1 = FSH2_0 + FSH2SZ;
static constexpr int FZROW  = 155056;
static constexpr int FH3SZ  = 30000;
static constexpr int FSWC0  = 60000;
static constexpr int FSWC1  = 64096;
static constexpr int FSPA   = 68192;
static constexpr int FLDS   = 155200;
static constexpr int FNGRP  = 32;
static constexpr int FNBLK  = NH_ * FNGRP;

__global__
__attribute__((amdgpu_flat_work_group_size(1024, 1024), amdgpu_waves_per_eu(4, 4)))
void fused_patch_kernel(
    const float* __restrict__ x1, const float* __restrict__ x2,
    const float* __restrict__ c1b, const float* __restrict__ c2b,
    const float* __restrict__ d2b, const float* __restrict__ d1b,
    const float* __restrict__ lin_w, const float* __restrict__ lin_b,
    const unsigned short* __restrict__ w1frag,
    const unsigned short* __restrict__ w2frag,
    const unsigned short* __restrict__ dw2frag,
    const float* __restrict__ dw1,
    float* __restrict__ recon)
{
    __shared__ alignas(16) char sbuf[FLDS];
    const int b   = blockIdx.x;
    const int pi  = b / FNGRP, g = b - pi * FNGRP;
    const int pj0 = 2 * g;
    const int npat = (pj0 + 1 < NH_) ? 2 : 1;
    const int n0  = pi * NH_ + pj0;
    const int n1  = (npat == 2) ? (n0 + 1) : n0;
    const int Y0  = pi * STR_, X0 = pj0 * STR_;
    const int t   = (int)threadIdx.x;
    const int wv  = t >> 6, lane = t & 63;
    const int ln15 = lane & 15, quad = lane >> 4;

    bf16x8 w1b[8];
    #pragma unroll
    for (int gg = 0; gg < 8; ++gg)
        w1b[gg] = *(const bf16x8*)(w1frag + (gg * 64 + lane) * 8);
    const float lw00 = lin_w[2 * n0], lw01 = lin_w[2 * n0 + 1];
    const float lw10 = lin_w[2 * n1], lw11 = lin_w[2 * n1 + 1];
    const float lbn0 = lin_b[n0], lbn1 = lin_b[n1];
    const float d1b0 = d1b[0];
    const f32x4 c1bq0 = *(const f32x4*)(c1b + quad * 4);
    f32x4 c1bq1 = (f32x4){0.f, 0.f, 0.f, 0.f};
    if (quad < 2) c1bq1 = *(const f32x4*)(c1b + 16 + quad * 4);
    const f32x4 d2bq0 = *(const f32x4*)(d2b + quad * 4);
    f32x4 d2bq1 = (f32x4){0.f, 0.f, 0.f, 0.f};
    if (quad < 2) d2bq1 = *(const f32x4*)(d2b + 16 + quad * 4);
    float dwp[4] = {0.f, 0.f, 0.f, 0.f};
    {
        int r0 = t >> 5, c0 = t & 31;
        if (c0 < 24) {
            dwp[0] = dw1[(c0 * 2 + 0) * 64 + r0];
            dwp[1] = dw1[(c0 * 2 + 1) * 64 + r0];
        }
        int k1 = t + 1024, r1 = k1 >> 5, c1 = k1 & 31;
        if (c1 < 24) {
            dwp[2] = dw1[(c1 * 2 + 0) * 64 + r1];
            dwp[3] = dw1[(c1 * 2 + 1) * 64 + r1];
        }
    }

    if (t < 4)       ((float*)(sbuf + FGAP16))[t] = 0.f;
    else if (t < 8)  ((float*)(sbuf + FSH2_1))[t - 4] = 0.f;
    else if (t < 42) ((float*)(sbuf + FZROW))[t - 8] = 0.f;
    #pragma unroll
    for (int it = 0; it < 3; ++it) {
        int k = t + it * 1024;
        int d = (k >= 1536) ? 1 : 0;
        int rem = k - d * 1536;
        int y = rem / 48, x = rem - y * 48;
        int xg = X0 + x; if (xg > W_ - 1) xg = W_ - 1;
        unsigned short bb = f2bf((d ? x2 : x1)[(Y0 + y) * W_ + xg]);
        int row = (d * 32 + y) * 48;
        ((unsigned short*)(sbuf + FCP0))[row + x] = bb;
        if (x > 0) ((unsigned short*)(sbuf + FCP1))[row + x - 1] = bb;
    }
    __syncthreads();

    for (int tl = wv; tl < 65; tl += 16) {
        const int rawm = tl * 16 + ln15;
        int m = rawm; if (m > 1024) m = 1024;
        int u = m / 41, v = m - u * 41;
        const char* cps = sbuf + ((v & 1) ? FCP1 : FCP0);
        const int vb2 = (v & ~1) * 2;
        f32x4 acc[2];
        acc[0] = (f32x4){0.f, 0.f, 0.f, 0.f};
        acc[1] = (f32x4){0.f, 0.f, 0.f, 0.f};
        #pragma unroll
        for (int kc = 0; kc < 4; ++kc) {
            const int idx8 = kc * 4 + quad;
            const int dd = idx8 >> 3, pp = idx8 & 7;
            const unsigned int* ap = (const unsigned int*)(cps + (dd * 32 + u + pp) * 96 + vb2);
            union { unsigned int u4[4]; bf16x8 v8; } af;
            af.u4[0] = ap[0]; af.u4[1] = ap[1]; af.u4[2] = ap[2]; af.u4[3] = ap[3];
            acc[0] = mfma_bf16(w1b[kc * 2 + 0], af.v8, acc[0]);
            acc[1] = mfma_bf16(w1b[kc * 2 + 1], af.v8, acc[1]);
        }
        if (rawm < 1025) {
            char* rowp = sbuf + rawm * 48;
            short4v p0;
            #pragma unroll
            for (int r = 0; r < 4; ++r) {
                float hv = acc[0][r] + c1bq0[r];
                hv = hv > 0.f ? hv : elu_neg(hv);
                p0[r] = (short)f2bf(hv);
            }
            *(short4v*)(rowp + quad * 8) = p0;
            if (quad < 2) {
                short4v p1;
                #pragma unroll
                for (int r = 0; r < 4; ++r) {
                    float hw = acc[1][r] + c1bq1[r];
                    hw = hw > 0.f ? hw : elu_neg(hw);
                    p1[r] = (short)f2bf(hw);
                }
                *(short4v*)(rowp + 32 + quad * 8) = p1;
            }
        }
    }
    __syncthreads();

    auto s2pass = [&](int t0, int t1) {
        const bool h1ok = (t1 < 56);
        int ab[2], loc[2], Pp[2];
        #pragma unroll
        for (int i = 0; i < 2; ++i) {
            int tt = i ? (h1ok ? t1 : t0) : t0;
            int P = (tt >= 28) ? 1 : 0;
            int lc = tt - P * 28;
            int mm = lc * 16 + ln15; if (mm > 440) mm = 440;
            int y = mm / 21, x = mm - y * 21;
            ab[i] = (y * 41 + P * 16 + x) * 48;
            loc[i] = lc; Pp[i] = P;
        }
        f32x4 acc2[2][4];
        #pragma unroll
        for (int i = 0; i < 2; ++i)
            #pragma unroll
            for (int nt = 0; nt < 4; ++nt)
                acc2[i][nt] = (f32x4){0.f, 0.f, 0.f, 0.f};
        const unsigned short* wb = w2frag + lane * 8;
        #pragma unroll
        for (int p = 0; p < 5; ++p) {
            #pragma unroll
            for (int q = 0; q < 5; ++q) {
                const int tap  = p * 5 + q;
                const int toff = (p * 41 + q) * 48;
                bf16x8 bfr[4];
                #pragma unroll
                for (int nt = 0; nt < 4; ++nt)
                    bfr[nt] = *(const bf16x8*)(wb + (tap * 4 + nt) * 512);
                {
                    bf16x8 a = *(const bf16x8*)(sbuf + ab[0] + toff + quad * 16);
                    #pragma unroll
                    for (int nt = 0; nt < 4; ++nt)
                        acc2[0][nt] = mfma_bf16(bfr[nt], a, acc2[0][nt]);
                }
                if (h1ok) {
                    bf16x8 a = *(const bf16x8*)(sbuf + ab[1] + toff + quad * 16);
                    #pragma unroll
                    for (int nt = 0; nt < 4; ++nt)
                        acc2[1][nt] = mfma_bf16(bfr[nt], a, acc2[1][nt]);
                }
            }
        }
        #pragma unroll
        for (int i = 0; i < 2; ++i) {
            if (i == 1 && !h1ok) continue;
            int rawpix = loc[i] * 16 + ln15;
            if (rawpix < 441) {
                char* rowp = sbuf + FSH2_0 + Pp[i] * FSH2SZ + rawpix * 120;
                #pragma unroll
                for (int nt = 0; nt < 4; ++nt) {
                    if (nt == 3 && quad == 3) continue;
                    const f32x4 bq = *(const f32x4*)(c2b + nt * 16 + quad * 4);
                    short4v pk;
                    #pragma unroll
                    for (int r = 0; r < 4; ++r)
                        pk[r] = (short)f2bf(fmaxf(acc2[i][nt][r] + bq[r], 0.f));
                    *(short4v*)(rowp + nt * 32 + quad * 8) = pk;
                }
            }
        }
    };
    s2pass(wv, wv + 16);
    s2pass(wv + 32, wv + 48);
    __syncthreads();

    f32x4 acc3[5][2];
    {
        #pragma unroll
        for (int i = 0; i < 5; ++i) {
            acc3[i][0] = (f32x4){0.f, 0.f, 0.f, 0.f};
            acc3[i][1] = (f32x4){0.f, 0.f, 0.f, 0.f};
        }
        int uarr[5], varr[5], aoff[5];
        bool mval[5];
        #pragma unroll
        for (int i = 0; i < 5; ++i) {
            int t5 = wv + 16 * i;
            int P = (t5 >= 40) ? 1 : 0;
            int lc = t5 - P * 40;
            int m = lc * 16 + ln15;
            mval[i] = (m < 625);
            int mc = mval[i] ? m : 0;
            uarr[i] = mc / 25; varr[i] = mc - uarr[i] * 25;
            aoff[i] = FSH2_0 + P * FSH2SZ + (uarr[i] * 21 + varr[i]) * 120;
        }
        const unsigned short* db = dw2frag + lane * 8;
        #pragma unroll
        for (int dy = 0; dy < 5; ++dy) {
            #pragma unroll
            for (int dx = 0; dx < 5; ++dx) {
                const int tap = dy * 5 + dx;
                const int t2o = (dy * 21 + dx) * 120;
                bf16x8 bc0 = *(const bf16x8*)(db + tap * 2048);
                bf16x8 bc1 = *(const bf16x8*)(db + tap * 2048 + 512);
                bf16x8 bc2 = *(const bf16x8*)(db + tap * 2048 + 1024);
                bf16x8 bc3 = *(const bf16x8*)(db + tap * 2048 + 1536);
                #pragma unroll
                for (int i = 0; i < 5; ++i) {
                    int yv = uarr[i] - dy, xv = varr[i] - dx;
                    bool ok = mval[i] && ((unsigned)yv < 21u) && ((unsigned)xv < 21u);
                    int ra = ok ? (aoff[i] - t2o) : FZROW;
                    const char* ap = sbuf + ra + quad * 16;
                    short4v lo0 = *(const short4v*)(ap);
                    short4v hi0 = *(const short4v*)(ap + 8);
                    bf16x8 a0 = __builtin_shufflevector(lo0, hi0, 0, 1, 2, 3, 4, 5, 6, 7);
                    acc3[i][0] = mfma_bf16(bc0, a0, acc3[i][0]);
                    acc3[i][1] = mfma_bf16(bc1, a0, acc3[i][1]);
                    short4v lo1 = *(const short4v*)(ap + 64);
                    short4v hi1 = *(const short4v*)(ap + 72);
                    bf16x8 a1 = __builtin_shufflevector(lo1, hi1, 0, 1, 2, 3, 4, 5, 6, 7);
                    acc3[i][0] = mfma_bf16(bc2, a1, acc3[i][0]);
                    acc3[i][1] = mfma_bf16(bc3, a1, acc3[i][1]);
                }
            }
        }
    }
    __syncthreads();

    float* sp = (float*)(sbuf + FSPA);
    {
        #pragma unroll
        for (int i = 0; i < 5; ++i) {
            int t5 = wv + 16 * i;
            int P = (t5 >= 40) ? 1 : 0;
            int lc = t5 - P * 40;
            int pix = lc * 16 + ln15;
            if (pix < 625) {
                char* rowp = sbuf + P * FH3SZ + pix * 48;
                short4v p0;
                #pragma unroll
                for (int r = 0; r < 4; ++r) {
                    float hv = acc3[i][0][r] + d2bq0[r];
                    hv = hv > 0.f ? hv : elu_neg(hv);
                    p0[r] = (short)f2bf(hv);
                }
                *(short4v*)(rowp + quad * 8) = p0;
                if (quad < 2) {
                    short4v p1;
                    #pragma unroll
                    for (int r = 0; r < 4; ++r) {
                        float hw = acc3[i][1][r] + d2bq1[r];
                        hw = hw > 0.f ? hw : elu_neg(hw);
                        p1[r] = (short)f2bf(hw);
                    }
                    *(short4v*)(rowp + 32 + quad * 8) = p1;
                }
            }
        }
    }
    {
        int r0 = t >> 5, c0 = t & 31;
        ((unsigned short*)(sbuf + FSWC0))[r0 * 32 + c0] = f2bf(lw00 * dwp[0] + lw01 * dwp[1]);
        ((unsigned short*)(sbuf + FSWC1))[r0 * 32 + c0] = f2bf(lw10 * dwp[0] + lw11 * dwp[1]);
        int k1 = t + 1024, r1 = k1 >> 5, c1 = k1 & 31;
        ((unsigned short*)(sbuf + FSWC0))[r1 * 32 + c1] = f2bf(lw00 * dwp[2] + lw01 * dwp[3]);
        ((unsigned short*)(sbuf + FSWC1))[r1 * 32 + c1] = f2bf(lw10 * dwp[2] + lw11 * dwp[3]);
    }
    sp[t] = 0.f; sp[t + 1024] = 0.f;
    __syncthreads();

    {
        int qoff[4];
        #pragma unroll
        for (int r = 0; r < 4; ++r) {
            int qr = quad * 4 + r;
            qoff[r] = (qr >> 3) * 32 + (qr & 7);
        }
        #pragma unroll
        for (int i = 0; i < 5; ++i) {
            int t5 = wv + 16 * i;
            int P = (t5 >= 40) ? 1 : 0;
            int lc = t5 - P * 40;
            int rawpix = lc * 16 + ln15;
            bool pok = (rawpix < 625);
            int pc = pok ? rawpix : 624;
            bf16x8 a = *(const bf16x8*)(sbuf + P * FH3SZ + pc * 48 + quad * 16);
            const char* swc = sbuf + (P ? FSWC1 : FSWC0);
            float* spP = sp + P * 1024;
            int uvbase = (pc / 25) * 32 + (pc % 25);
            #pragma unroll
            for (int nt = 0; nt < 4; ++nt) {
                bf16x8 wbv = *(const bf16x8*)(swc + (nt * 16 + ln15) * 64 + quad * 16);
                f32x4 acc4 = (f32x4){0.f, 0.f, 0.f, 0.f};
                acc4 = mfma_bf16(wbv, a, acc4);
                if (pok) {
                    #pragma unroll
                    for (int r = 0; r < 4; ++r)
                        atomicAdd(&spP[uvbase + nt * 64 + qoff[r]], acc4[r]);
                }
            }
        }
    }
    __syncthreads();

    {
        int yy = t >> 5, xx = t & 31;
        float ob0 = d1b0 * (lw00 + lw01) + lbn0;
        atomicAdd(&recon[(Y0 + yy) * W_ + X0 + xx], sp[t] + ob0);
        if (npat == 2) {
            float ob1 = d1b0 * (lw10 + lw11) + lbn1;
            atomicAdd(&recon[(Y0 + yy) * W_ + X0 + 16 + xx], sp[t + 1024] + ob1);
        }
    }
}

// ---------------------------------------------------------------------------
__global__ void prep_kernel(const float* __restrict__ c1w,
                            const float* __restrict__ c2w,
                            const float* __restrict__ d2w,
                            unsigned short* __restrict__ w1frag,
                            unsigned short* __restrict__ w2frag,
                            unsigned short* __restrict__ dw2frag)
{
    int i = blockIdx.x * blockDim.x + threadIdx.x;
    if (i < 51200) {
        int j = i & 7, lane = (i >> 3) & 63;
        int ln15 = lane & 15, quad = lane >> 4;
        if (i < 4096) {   // conv1
            int g = i >> 9;
            int kc = g >> 1, nt = g & 1;
            int nn = nt * 16 + ln15, k = kc * 32 + quad * 8 + j;
            w1frag[i] = f2bf((nn < 24) ? c1w[nn * 128 + k] : 0.f);
        }
        {   // conv2
            int nt = (i >> 9) & 3, tap = i >> 11;
            int o = nt * 16 + ln15, c = quad * 8 + j;
            float v = (o < 60 && c < 24) ? c2w[(o * 24 + c) * 25 + tap] : 0.f;
            w2frag[i] = f2bf(v);
        }
        {   // deconv2
            int nt = (i >> 9) & 1, kc = (i >> 10) & 1, tap = i >> 11;
            int k = kc * 32 + quad * 8 + j, c = nt * 16 + ln15;
            float v = (k < 60 && c < 24) ? d2w[(k * 24 + c) * 25 + tap] : 0.f;
            dw2frag[i] = f2bf(v);
        }
    }
}

__global__ void finalize_kernel(const float* __restrict__ x2,
                                const float* __restrict__ l1w,
                                float* __restrict__ out)
{
    int i = blockIdx.x * blockDim.x + threadIdx.x;
    if (i < H_ * W_) {
        float r = out[i];
        out[i] = x2[i] - r * l1w[0];
    }
}

extern "C" void kernel_launch(void* const* d_in, const int* in_sizes, int n_in,
                              void* d_out, int out_size, void* d_ws, size_t ws_size,
                              hipStream_t stream)
{
    const float* x1  = (const float*)d_in[0];
    const float* x2  = (const float*)d_in[1];
    const float* c1w = (const float*)d_in[2];
    const float* c1b = (const float*)d_in[3];
    const float* c2w = (const float*)d_in[4];
    const float* c2b = (const float*)d_in[5];
    const float* d2w = (const float*)d_in[6];
    const float* d2b = (const float*)d_in[7];
    const float* d1w = (const float*)d_in[8];
    const float* d1b = (const float*)d_in[9];
    const float* lw  = (const float*)d_in[10];
    const float* lb  = (const float*)d_in[11];
    const float* l1w = (const float*)d_in[12];

    float*          out     = (float*)d_out;
    unsigned short* w1frag  = (unsigned short*)d_ws;                      // 8192 B
    unsigned short* w2frag  = (unsigned short*)((char*)d_ws + 8192);      // 102400 B
    unsigned short* dw2frag = (unsigned short*)((char*)d_ws + 110592);    // 102400 B

    hipMemsetAsync(d_out, 0, (size_t)H_ * W_ * sizeof(float), stream);
    prep_kernel<<<100, 512, 0, stream>>>(c1w, c2w, d2w, w1frag, w2frag, dw2frag);

    if (ws_size >= WS_NEED) {
        unsigned short* h1 = (unsigned short*)((char*)d_ws + FRAG_BYTES);
        unsigned short* h2 = (unsigned short*)((char*)d_ws + FRAG_BYTES + H1_BYTES);
        unsigned short* h3 = h1;   // alias: h1 dead after k_conv2
        k_conv1<<<NPATCH_, 256, 0, stream>>>(x1, x2, c1b, w1frag, h1);
        k_conv2<<<NPATCH_, 256, 0, stream>>>(c2b, w2frag, h1, h2);
        k_deconv2<<<NPATCH_, 512, 0, stream>>>(d2b, dw2frag, h2, h3);
        k_epilogue<<<NPATCH_, 256, 0, stream>>>(d1b, lw, lb, d1w, h3, out);
    } else {
        fused_patch_kernel<<<FNBLK, 1024, 0, stream>>>(x1, x2, c1b, c2b, d2b, d1b,
                                                       lw, lb, w1frag, w2frag, dw2frag,
                                                       d1w, out);
    }
    finalize_kernel<<<(H_ * W_ + 255) / 256, 256, 0, stream>>>(x2, l1w, out);
}